// Round 11
// baseline (472.654 us; speedup 1.0000x reference)
//
#include <hip/hip_runtime.h>
#include <math.h>

// ---------------------------------------------------------------------------
// ActorCriticPolicy fused forward — FP16 in/out, fp32 internal (R6+ verified).
//   E=100, H=256, L=4 res blocks, B=1024, A=256.
//   d_out: logits (1024x256 fp16) then value (1024 fp16).
//
// R20: 64-row blocks, wave = 64r x 32c (acc[4][2] = 32 AGPR). Traffic
// accounting found the hidden co-limiter: each block reads the FULL weight
// set (~761 KB) regardless of rows -> 8256 blocks = 6.3 GB from L2 in
// 234us = 27 TB/s = 78% of the 34.5 TB/s L2 ceiling. Doubling rows/block
// halves L2 weight traffic AND barriers/row AND GEMM mechanics/row.
// Cost: occupancy 63->~50% ((512,4) cap 128, live ~92-108 regs, clean;
// 2 blocks/CU; LDS 50.7KB). Unlike R11's 64-row config: no B duplication
// (R11's row-split waves read each matrix 2x), ping-pong unroll-2 kept.
// Falsification: trunk >=240 -> occupancy loss dominates, revert to R19.
//
// R19: 2-step DPP quad reduce + fma-form LN + setprio (trunk 242->234).
// R18: ping-pong unroll-2 GEMM k-loop (VALUBusy 58->50, trunk 254->242).
// R17: reg-cap sweet spot; depth-1 B prefetch + f16 register residual.
// R13/R12 lesson: spill poison — check FETCH/WRITE on every reg change.
// R11: ~225us residue is harness floor. R10: merged grid; logits epilogue.
//
// Wave w of 8: rows 0..63 (mt 0..3), cols w*32..+31 (2 n-tiles). A-frags
// from LDS h16[64][264]; B-frags from packed global (L2), depth-1 prefetch.
// Fragment layouts (R7-verified): A: m=lane&15, k=(lane>>4)*8+j;
// B: n=lane&15, k=(lane>>4)*8+j; C/D: col=lane&15, row=(lane>>4)*4+reg.
//
// Packed layout (f16 units), per net [WIN | L0..L3 | W1head]:
//   policy: 0 win, 32768+l*65536 layers, W1@294912 (16 nt), W2@360448 (7 nt)
//   value:  base 389120: win, layers, W1@+294912 (8 nt). total 716800 f16.
// ---------------------------------------------------------------------------

typedef unsigned short u16;
typedef _Float16 f16;
typedef _Float16 half8 __attribute__((ext_vector_type(8)));
typedef float floatx4 __attribute__((ext_vector_type(4)));

#define E_DIM  100
#define H_DIM  256
#define NLAYER 4
#define BATCH  1024
#define NACT   256
#define NROWS_ACT (BATCH * NACT)
#define LN_EPS 1e-5f

#define NET_WIN  0
#define NET_WL(l) (32768 + (l) * 65536)
#define NET_W1   294912
#define NET_W2P  360448
#define POL_SZ   389120
#define VAL_BASE POL_SZ
#define PACK_TOTAL (POL_SZ + 327680)

#define TROWS 64                         // rows per block
#define ACT_BLOCKS (NROWS_ACT / TROWS)   // 4096
#define OBS_BLOCKS (BATCH / TROWS)       // 16 (policy) + 16 (value)

#define WS_VROWS   16
#define WS_ENCOBS  (16 + NROWS_ACT * 4)
#define WS_PACK    (WS_ENCOBS + BATCH * E_DIM * 4)
#define WS_ENCACT  (WS_PACK + PACK_TOTAL * 2)   // f16[NROWS_ACT * 112] ~ 59 MB

__device__ __forceinline__ u16 f2h_u16(float f) {
  union { u16 u; f16 h; } c; c.h = (f16)f; return c.u;
}

__device__ __forceinline__ float wsum(float v) {
#pragma unroll
  for (int off = 1; off < 64; off <<= 1) v += __shfl_xor(v, off, 64);
  return v;
}

// DPP add — VALU-only, no DS pipe traffic.
template <int CTRL>
__device__ __forceinline__ float dpp_add(float v) {
  const int t = __builtin_amdgcn_update_dpp(0, __float_as_int(v), CTRL, 0xF, 0xF, true);
  return v + __int_as_float(t);
}
// 2-step quad sum: every lane gets the sum of its aligned physical quad.
__device__ __forceinline__ float dpp_red4(float v) {
  v = dpp_add<0xB1>(v);    // quad_perm [1,0,3,2]  (xor 1)
  v = dpp_add<0x4E>(v);    // quad_perm [2,3,0,1]  (xor 2)
  return v;
}

__global__ void zero_counter_kernel(int* counter) { *counter = 0; }

// Wave-aggregated compaction (R11).
__global__ void compact_kernel(const int* __restrict__ mask, int n,
                               int* __restrict__ counter,
                               int* __restrict__ rows,
                               u16* __restrict__ logits)
{
  const int i = blockIdx.x * blockDim.x + threadIdx.x;
  const int lane = threadIdx.x & 63;
  bool valid = false;
  if (i < n) {
    valid = (mask[i] != 0);
    if (!valid) logits[i] = (u16)0xFBFF;   // -65504, finite fp16 -inf stand-in
  }
  const unsigned long long bal = __ballot(valid);
  const int cnt = __popcll(bal);
  int base = 0;
  if (lane == 0 && cnt) base = atomicAdd(counter, cnt);
  base = __shfl(base, 0, 64);
  if (valid) {
    const int off = __popcll(bal & ((1ull << lane) - 1ull));
    rows[base + off] = i;
  }
}

__device__ __forceinline__ f16 pack_elem(const f16* __restrict__ W, int li,
                                         int K, int N, int Np)
{
  const int j = li & 7, lane = (li >> 3) & 63, tile = li >> 9;
  const int ntiles = Np >> 4;
  const int k0 = (tile / ntiles) * 32, n0 = (tile % ntiles) * 16;
  const int k = k0 + ((lane >> 4) << 3) + j, n = n0 + (lane & 15);
  return (k < K && n < N) ? W[k * N + n] : (f16)0.f;
}

__global__ void pack_all_kernel(
    const f16* __restrict__ pw_in, const f16* __restrict__ pW,
    const f16* __restrict__ po_w1, const f16* __restrict__ po_w2,
    const f16* __restrict__ vw_in, const f16* __restrict__ vW,
    const f16* __restrict__ vo_w1, f16* __restrict__ dst)
{
  const int i = blockIdx.x * blockDim.x + threadIdx.x;
  if (i >= PACK_TOTAL) return;
  f16 v;
  if (i < 32768)        v = pack_elem(pw_in, i, E_DIM, H_DIM, 256);
  else if (i < 294912) { const int r = i - 32768, l = r >> 16;
                         v = pack_elem(pW + (size_t)l * 65536, r & 65535, 256, 256, 256); }
  else if (i < 360448)  v = pack_elem(po_w1, i - 294912, 256, 256, 256);
  else if (i < 389120)  v = pack_elem(po_w2, i - 360448, 256, E_DIM, 112);
  else if (i < 421888)  v = pack_elem(vw_in, i - 389120, E_DIM, H_DIM, 256);
  else if (i < 684032) { const int r = i - 421888, l = r >> 16;
                         v = pack_elem(vW + (size_t)l * 65536, r & 65535, 256, 256, 256); }
  else                  v = pack_elem(vo_w1, i - 684032, 256, 128, 128);
  dst[i] = v;
}

// wave GEMM: KT k-steps of 32 (KT even), 4 m-tiles (64 rows), NTC n-tiles,
// NTA = total n-tiles. Ping-pong unroll-2 + depth-1 B prefetch + setprio.
template <int KT, int NTC, int NTA>
__device__ __forceinline__ void wave_gemm_t(
    const f16* __restrict__ pw, const f16* __restrict__ h16,
    int q, int l15, int lane, int nt_base, floatx4 acc[][2])
{
  static_assert((KT & 1) == 0, "KT must be even");
  const f16* pl = pw + (size_t)nt_base * 512 + lane * 8;
  const f16* pa = h16 + l15 * 264 + q * 8;
  const size_t KS = (size_t)NTA * 512;
  half8 b0[NTC], b1[NTC];
#pragma unroll
  for (int t = 0; t < NTC; ++t) b0[t] = *(const half8*)(pl + t * 512);
#pragma unroll 1
  for (int kp = 0; kp < KT / 2 - 1; ++kp) {
#pragma unroll
    for (int t = 0; t < NTC; ++t) b1[t] = *(const half8*)(pl + KS + t * 512);
    {
      half8 a[4];
#pragma unroll
      for (int mt = 0; mt < 4; ++mt) a[mt] = *(const half8*)(pa + mt * 16 * 264);
      __builtin_amdgcn_s_setprio(1);
#pragma unroll
      for (int mt = 0; mt < 4; ++mt)
#pragma unroll
        for (int t = 0; t < NTC; ++t)
          acc[mt][t] = __builtin_amdgcn_mfma_f32_16x16x32_f16(a[mt], b0[t], acc[mt][t], 0, 0, 0);
      __builtin_amdgcn_s_setprio(0);
    }
#pragma unroll
    for (int t = 0; t < NTC; ++t) b0[t] = *(const half8*)(pl + 2 * KS + t * 512);
    {
      half8 a[4];
#pragma unroll
      for (int mt = 0; mt < 4; ++mt) a[mt] = *(const half8*)(pa + mt * 16 * 264 + 32);
      __builtin_amdgcn_s_setprio(1);
#pragma unroll
      for (int mt = 0; mt < 4; ++mt)
#pragma unroll
        for (int t = 0; t < NTC; ++t)
          acc[mt][t] = __builtin_amdgcn_mfma_f32_16x16x32_f16(a[mt], b1[t], acc[mt][t], 0, 0, 0);
      __builtin_amdgcn_s_setprio(0);
    }
    pl += 2 * KS;
    pa += 64;
  }
  // final pair (no further prefetch)
#pragma unroll
  for (int t = 0; t < NTC; ++t) b1[t] = *(const half8*)(pl + KS + t * 512);
  {
    half8 a[4];
#pragma unroll
    for (int mt = 0; mt < 4; ++mt) a[mt] = *(const half8*)(pa + mt * 16 * 264);
    __builtin_amdgcn_s_setprio(1);
#pragma unroll
    for (int mt = 0; mt < 4; ++mt)
#pragma unroll
      for (int t = 0; t < NTC; ++t)
        acc[mt][t] = __builtin_amdgcn_mfma_f32_16x16x32_f16(a[mt], b0[t], acc[mt][t], 0, 0, 0);
    __builtin_amdgcn_s_setprio(0);
  }
  {
    half8 a[4];
#pragma unroll
    for (int mt = 0; mt < 4; ++mt) a[mt] = *(const half8*)(pa + mt * 16 * 264 + 32);
    __builtin_amdgcn_s_setprio(1);
#pragma unroll
    for (int mt = 0; mt < 4; ++mt)
#pragma unroll
      for (int t = 0; t < NTC; ++t)
        acc[mt][t] = __builtin_amdgcn_mfma_f32_16x16x32_f16(a[mt], b1[t], acc[mt][t], 0, 0, 0);
    __builtin_amdgcn_s_setprio(0);
  }
}

// trunk: input layer + NLAYER residual layers.
// RREG=true: residual in f16 registers (policy). false: fp32 resf (value).
// 8 waves; wave w: rows 0..63, cols w*32..+31. 3 barriers/layer.
template <bool RREG>
__device__ __forceinline__ void run_trunk(
    const f16* __restrict__ packN,
    const f16* __restrict__ b_in, const f16* __restrict__ g_in, const f16* __restrict__ be_in,
    const f16* __restrict__ Br, const f16* __restrict__ Gr, const f16* __restrict__ Ber,
    f16* __restrict__ h16, float2 (*red)[32], float2* __restrict__ stats,
    floatx4 acc[4][2], float* __restrict__ resf, f16* __restrict__ res16,
    int tid, int q, int l15, int w, int n0)
{
#pragma unroll 1
  for (int l = 0; l <= NLAYER; ++l) {
    const f16* pw; const f16* bias; const f16* g; const f16* be;
    if (l == 0) { pw = packN + NET_WIN; bias = b_in; g = g_in; be = be_in; }
    else {
      pw = packN + NET_WL(l - 1); bias = Br + (l - 1) * H_DIM;
      g = Gr + (l - 1) * H_DIM;   be = Ber + (l - 1) * H_DIM;
    }
    {
      const float bv0 = (float)bias[n0 + l15];
      const float bv1 = (float)bias[n0 + 16 + l15];
#pragma unroll
      for (int mt = 0; mt < 4; ++mt) {
        acc[mt][0] = (floatx4){bv0, bv0, bv0, bv0};
        acc[mt][1] = (floatx4){bv1, bv1, bv1, bv1};
      }
    }
    if (l == 0) wave_gemm_t<4, 2, 16>(pw, h16, q, l15, tid & 63, w * 2, acc);
    else        wave_gemm_t<8, 2, 16>(pw, h16, q, l15, tid & 63, w * 2, acc);

    // partial sums over this wave's 32 cols — 2-step DPP (quad sums),
    // quad leaders write red[R][w*4 + quad]
#pragma unroll
    for (int mt = 0; mt < 4; ++mt)
#pragma unroll
      for (int reg = 0; reg < 4; ++reg) {
        const float v0 = fmaxf(acc[mt][0][reg], 0.f);
        const float v1 = fmaxf(acc[mt][1][reg], 0.f);
        acc[mt][0][reg] = v0; acc[mt][1][reg] = v1;   // keep relu'd
        const float s  = dpp_red4(v0 + v1);
        const float s2 = dpp_red4(v0 * v0 + v1 * v1);
        if ((l15 & 3) == 0) {
          const int R = mt * 16 + q * 4 + reg;
          red[R][w * 4 + (l15 >> 2)] = (float2){s, s2};
        }
      }
    __syncthreads();

    // centralized row stats: 64 threads, one row each (32 partials/row)
    if (tid < TROWS) {
      const float4* rp = (const float4*)&red[tid][0];
      float s = 0.f, s2 = 0.f;
#pragma unroll
      for (int i = 0; i < 16; ++i) {
        const float4 r = rp[i];
        s += r.x + r.z; s2 += r.y + r.w;
      }
      const float mean = s * (1.f / 256.f);
      const float var  = s2 * (1.f / 256.f) - mean * mean;
      stats[tid] = (float2){mean, 1.f / sqrtf(var + LN_EPS)};
    }
    __syncthreads();

    const float gf0 = (float)g[n0 + l15],       gf1 = (float)g[n0 + 16 + l15];
    const float bf0 = (float)be[n0 + l15],      bf1 = (float)be[n0 + 16 + l15];
#pragma unroll
    for (int mt = 0; mt < 4; ++mt)
#pragma unroll
      for (int reg = 0; reg < 4; ++reg) {
        const int R = mt * 16 + q * 4 + reg;
        const float2 st = stats[R];
        const float a0c = st.y * gf0;
        const float b0c = fmaf(-st.x, a0c, bf0);
        const float a1c = st.y * gf1;
        const float b1c = fmaf(-st.x, a1c, bf1);
#pragma unroll
        for (int t = 0; t < 2; ++t) {
          const int col = n0 + t * 16 + l15;
          const int ri = (mt * 2 + t) * 4 + reg;
          const float vv = fmaf(acc[mt][t][reg],
                                t == 0 ? a0c : a1c, t == 0 ? b0c : b1c);
          float rprev;
          if (l == 0) rprev = 0.f;
          else rprev = RREG ? (float)res16[ri] : resf[ri];
          const float r = rprev + vv;
          if (RREG) res16[ri] = (f16)r; else resf[ri] = r;
          h16[R * 264 + col] = (f16)r;
        }
      }
    __syncthreads();
  }
}

// policy heads: h1 = relu(h @ w1 + b1); enc = h1 @ w2 + b2 -> encf (64x112 f32)
__device__ __forceinline__ void policy_heads(
    const f16* __restrict__ packN,
    const f16* __restrict__ b1, const f16* __restrict__ b2,
    f16* __restrict__ h16, floatx4 acc[4][2],
    int tid, int q, int l15, int w, int n0)
{
  {
    const float bv0 = (float)b1[n0 + l15];
    const float bv1 = (float)b1[n0 + 16 + l15];
#pragma unroll
    for (int mt = 0; mt < 4; ++mt) {
      acc[mt][0] = (floatx4){bv0, bv0, bv0, bv0};
      acc[mt][1] = (floatx4){bv1, bv1, bv1, bv1};
    }
  }
  wave_gemm_t<8, 2, 16>(packN + NET_W1, h16, q, l15, tid & 63, w * 2, acc);
  __syncthreads();
#pragma unroll
  for (int mt = 0; mt < 4; ++mt)
#pragma unroll
    for (int reg = 0; reg < 4; ++reg) {
      const int R = mt * 16 + q * 4 + reg;
#pragma unroll
      for (int t = 0; t < 2; ++t)
        h16[R * 264 + n0 + t * 16 + l15] = (f16)fmaxf(acc[mt][t][reg], 0.f);
    }
  __syncthreads();

  // W2: 7 n-tiles; waves 0..6 take one tile each
  if (w < 7) {
    const int col = w * 16 + l15;
    const float bv = (col < E_DIM) ? (float)b2[col] : 0.f;
#pragma unroll
    for (int mt = 0; mt < 4; ++mt)
      acc[mt][0] = (floatx4){bv, bv, bv, bv};
    wave_gemm_t<8, 1, 7>(packN + NET_W2P, h16, q, l15, tid & 63, w, acc);
  }
  __syncthreads();

  float* encf = (float*)h16;   // 64 x 112 fp32 (28672 B <= 33792 B)
  if (w < 7) {
#pragma unroll
    for (int mt = 0; mt < 4; ++mt)
#pragma unroll
      for (int reg = 0; reg < 4; ++reg) {
        const int R = mt * 16 + q * 4 + reg;
        encf[R * 112 + w * 16 + l15] = acc[mt][0][reg];
      }
  }
  __syncthreads();
}

// Merged trunk kernel (8 waves, 64 rows per block, cap 128, no spill).
//  blockIdx 0..15  : policy obs-encode (1024 rows)  -> enc_obs (f32)
//  blockIdx 16..31 : value net (1024 rows)          -> value   (f16)
//  blockIdx 32..   : act-encode on compacted rows   -> enc_act (f16, ws)
__global__ __launch_bounds__(512, 4)
void trunk_kernel(
    const f16* __restrict__ obs, const f16* __restrict__ xact,
    const int* __restrict__ vrows, const int* __restrict__ counter,
    const f16* __restrict__ packP, const f16* __restrict__ packV,
    // policy params
    const f16* __restrict__ pb_in, const f16* __restrict__ pg_in, const f16* __restrict__ pbe_in,
    const f16* __restrict__ pB, const f16* __restrict__ pG, const f16* __restrict__ pBe,
    const f16* __restrict__ po_b1, const f16* __restrict__ po_b2,
    // value params
    const f16* __restrict__ vb_in, const f16* __restrict__ vg_in, const f16* __restrict__ vbe_in,
    const f16* __restrict__ vB, const f16* __restrict__ vG, const f16* __restrict__ vBe,
    const f16* __restrict__ vo_b1, const f16* __restrict__ vo_b2, const f16* __restrict__ vo_w2,
    float* __restrict__ enc_obs_out, f16* __restrict__ enc_act_out,
    u16* __restrict__ value_out)
{
  __shared__ __align__(16) f16 h16[TROWS * 264];
  __shared__ __align__(16) float2 red[TROWS][32];
  __shared__ float2 stats[TROWS];

  const int tid  = threadIdx.x;
  const int lane = tid & 63;
  const int w    = tid >> 6;          // 0..7
  const int l15 = lane & 15, q = lane >> 4;
  const int n0 = w * 32;              // wave cols: w*32 .. w*32+31

  floatx4 acc[4][2];

  if (blockIdx.x >= 2 * OBS_BLOCKS) {
    // ---------------- act-encode role ----------------
    const int count = *counter;
    const int base = (blockIdx.x - 2 * OBS_BLOCKS) * TROWS;
    if (base >= count) return;

    for (int idx = tid; idx < TROWS * 128; idx += 512) {
      const int r = idx >> 7, c = idx & 127;
      const int gr = base + r;
      f16 v = (f16)0.f;
      if (c < E_DIM && gr < count) v = xact[(size_t)vrows[gr] * E_DIM + c];
      h16[r * 264 + c] = v;
    }
    __syncthreads();

    f16 res16[32];
    run_trunk<true>(packP, pb_in, pg_in, pbe_in, pB, pG, pBe, h16, red, stats,
                    acc, nullptr, res16, tid, q, l15, w, n0);
    policy_heads(packP, po_b1, po_b2, h16, acc, tid, q, l15, w, n0);

    const float* encf = (const float*)h16;
    for (int idx = tid; idx < TROWS * 112; idx += 512) {
      const int r = idx / 112, c = idx - r * 112;
      enc_act_out[(size_t)(base + r) * 112 + c] = (f16)encf[r * 112 + c];
    }
    return;
  }

  // ---------------- obs / value roles ----------------
  const bool isv = blockIdx.x >= OBS_BLOCKS;
  const int base = (isv ? (blockIdx.x - OBS_BLOCKS) : blockIdx.x) * TROWS;

  for (int idx = tid; idx < TROWS * 128; idx += 512) {
    const int r = idx >> 7, c = idx & 127;
    h16[r * 264 + c] = (c < E_DIM) ? obs[(size_t)(base + r) * E_DIM + c] : (f16)0.f;
  }
  __syncthreads();

  if (!isv) {
    f16 res16[32];
    run_trunk<true>(packP, pb_in, pg_in, pbe_in, pB, pG, pBe, h16, red, stats,
                    acc, nullptr, res16, tid, q, l15, w, n0);
    policy_heads(packP, po_b1, po_b2, h16, acc, tid, q, l15, w, n0);
    const float* encf = (const float*)h16;
    for (int idx = tid; idx < TROWS * E_DIM; idx += 512) {
      const int r = idx / E_DIM, c = idx - r * E_DIM;
      enc_obs_out[(size_t)(base + r) * E_DIM + c] = encf[r * 112 + c];
    }
  } else {
    float resf[32];
    run_trunk<false>(packV, vb_in, vg_in, vbe_in, vB, vG, vBe, h16, red, stats,
                     acc, resf, nullptr, tid, q, l15, w, n0);
    // value head1: relu(h @ vo_w1 + vo_b1), N=128 = 8 n-tiles, 1 per wave
    {
      const float bv = (float)vo_b1[w * 16 + l15];
#pragma unroll
      for (int mt = 0; mt < 4; ++mt)
        acc[mt][0] = (floatx4){bv, bv, bv, bv};
    }
    wave_gemm_t<8, 1, 8>(packV + NET_W1, h16, q, l15, lane, w, acc);
    __syncthreads();
    float* encf = (float*)h16;   // 64 x 128 fp32 (32768 B <= 33792 B)
#pragma unroll
    for (int mt = 0; mt < 4; ++mt)
#pragma unroll
      for (int reg = 0; reg < 4; ++reg) {
        const int R = mt * 16 + q * 4 + reg;
        encf[R * 128 + w * 16 + l15] = fmaxf(acc[mt][0][reg], 0.f);
      }
    __syncthreads();
    const float w2a = (float)vo_w2[lane], w2b = (float)vo_w2[lane + 64];
    const float b2v = (float)vo_b2[0];
    for (int j = 0; j < 8; ++j) {
      const int r = w * 8 + j;
      const float p = encf[r * 128 + lane] * w2a + encf[r * 128 + lane + 64] * w2b;
      const float tot = wsum(p);
      if (lane == 0) value_out[base + r] = f2h_u16(tot + b2v);
    }
  }
}

// epilogue: logits[vrow] = (enc_obs[bb] . enc_act[gr]) / sqrt(E)
__global__ __launch_bounds__(256)
void logits_kernel(const int* __restrict__ vrows, const int* __restrict__ counter,
                   const f16* __restrict__ enc_act, const float* __restrict__ enc_obs,
                   u16* __restrict__ logits)
{
  const int count = *counter;
  const int lane = threadIdx.x & 63;
  const int nw = (gridDim.x * blockDim.x) >> 6;
  for (int gr = (blockIdx.x * blockDim.x + threadIdx.x) >> 6; gr < count; gr += nw) {
    const int vrow = vrows[gr];
    const int bb = vrow >> 8;   // A = 256
    const float* ob = enc_obs + (size_t)bb * E_DIM;
    const f16*   ar = enc_act + (size_t)gr * 112;
    float p = (float)ar[lane] * ob[lane];
    if (lane + 64 < E_DIM) p += (float)ar[lane + 64] * ob[lane + 64];
    const float tot = wsum(p);
    if (lane == 0) logits[vrow] = f2h_u16(tot * 0.1f);   // 1/sqrt(100)
  }
}

// ============================ launch =======================================
extern "C" void kernel_launch(void* const* d_in, const int* in_sizes, int n_in,
                              void* d_out, int out_size, void* d_ws, size_t ws_size,
                              hipStream_t stream)
{
  const f16* obs   = (const f16*)d_in[0];
  const f16* actE  = (const f16*)d_in[1];
  const int* mask  = (const int*)d_in[2];
  const f16* pw_in = (const f16*)d_in[3];
  const f16* pb_in = (const f16*)d_in[4];
  const f16* pg_in = (const f16*)d_in[5];
  const f16* pbe_in= (const f16*)d_in[6];
  const f16* pW    = (const f16*)d_in[7];
  const f16* pB    = (const f16*)d_in[8];
  const f16* pG    = (const f16*)d_in[9];
  const f16* pBe   = (const f16*)d_in[10];
  const f16* po_w1 = (const f16*)d_in[11];
  const f16* po_b1 = (const f16*)d_in[12];
  const f16* po_w2 = (const f16*)d_in[13];
  const f16* po_b2 = (const f16*)d_in[14];
  const f16* vw_in = (const f16*)d_in[15];
  const f16* vb_in = (const f16*)d_in[16];
  const f16* vg_in = (const f16*)d_in[17];
  const f16* vbe_in= (const f16*)d_in[18];
  const f16* vW    = (const f16*)d_in[19];
  const f16* vB    = (const f16*)d_in[20];
  const f16* vG    = (const f16*)d_in[21];
  const f16* vBe   = (const f16*)d_in[22];
  const f16* vo_w1 = (const f16*)d_in[23];
  const f16* vo_b1 = (const f16*)d_in[24];
  const f16* vo_w2 = (const f16*)d_in[25];
  const f16* vo_b2 = (const f16*)d_in[26];

  u16* logits = (u16*)d_out;
  u16* value  = (u16*)d_out + NROWS_ACT;

  int*   counter = (int*)d_ws;
  int*   vrows   = (int*)((char*)d_ws + WS_VROWS);
  float* enc_obs = (float*)((char*)d_ws + WS_ENCOBS);
  f16*   packW   = (f16*)((char*)d_ws + WS_PACK);
  f16*   enc_act = (f16*)((char*)d_ws + WS_ENCACT);

  zero_counter_kernel<<<1, 1, 0, stream>>>(counter);
  compact_kernel<<<NROWS_ACT / 256, 256, 0, stream>>>(mask, NROWS_ACT, counter,
                                                      vrows, logits);
  pack_all_kernel<<<(PACK_TOTAL + 255) / 256, 256, 0, stream>>>(
      pw_in, pW, po_w1, po_w2, vw_in, vW, vo_w1, packW);

  trunk_kernel<<<ACT_BLOCKS + 2 * OBS_BLOCKS, 512, 0, stream>>>(
      obs, actE, vrows, counter, packW, packW + VAL_BASE,
      pb_in, pg_in, pbe_in, pB, pG, pBe, po_b1, po_b2,
      vb_in, vg_in, vbe_in, vB, vG, vBe, vo_b1, vo_b2, vo_w2,
      enc_obs, enc_act, value);

  logits_kernel<<<2048, 256, 0, stream>>>(vrows, counter, enc_act, enc_obs, logits);
}

// Round 13
// 462.872 us; speedup vs baseline: 1.0211x; 1.0211x over previous
//
#include <hip/hip_runtime.h>
#include <math.h>

// ---------------------------------------------------------------------------
// ActorCriticPolicy fused forward — FP16 in/out, fp32 internal (R6+ verified).
//   E=100, H=256, L=4 res blocks, B=1024, A=256.
//   d_out: logits (1024x256 fp16) then value (1024 fp16).
//
// R22: resubmit of R21 (R19 revert) — R21 bench failed on GPU acquisition
// (infra), no data. R19 = best measured: 459.2us total, trunk 234us.
//
// R20 (64-row blocks, halved L2 weight traffic) was clean but SLOWER
// (trunk 244, occ 63->40): falsified the L2-bandwidth co-limiter theory.
// Structure-sweep ledger:
//   8w x 64r @96reg: 302 | 4w x 32r @96reg: 297 | 8w x 32r cap64+spill: 267
//   8w x 32r cap80 clean (R19): 234  <- optimum | 8w x 64r cap128: 244
// R19 sits at the empirical optimum of {tile, occupancy, regs}: tighter
// regs spill, bigger tiles expose latency. Remaining idle (~30%) is the
// 3-barrier/layer dependence chain; candidates to remove it cost more
// VALU/DS than they save. ~225us of total is harness floor.
//
// R19: 2-step DPP quad reduce + fma-form LN + setprio (242->234).
// R18: ping-pong unroll-2 GEMM k-loop (VALUBusy 58->50, 254->242).
// R17: (512,6) 80-reg cap sweet spot; depth-1 B prefetch + f16 reg
// residual, zero spill. R16: unroll-1 (full-unroll hoisting spilled @64).
// R13/R12 lesson: spill poison — check FETCH/WRITE on every reg change.
// R11: ~225us residue is harness floor. R10: merged grid; logits epilogue.
//
// Wave w of 8: rows 0..31, cols w*32..+31 (2 n-tiles). A-frags from LDS
// h16[32][264]; B-frags from packed global (L2-resident), depth-1 prefetch.
// Fragment layouts (R7-verified): A: m=lane&15, k=(lane>>4)*8+j;
// B: n=lane&15, k=(lane>>4)*8+j; C/D: col=lane&15, row=(lane>>4)*4+reg.
//
// Packed layout (f16 units), per net [WIN | L0..L3 | W1head]:
//   policy: 0 win, 32768+l*65536 layers, W1@294912 (16 nt), W2@360448 (7 nt)
//   value:  base 389120: win, layers, W1@+294912 (8 nt). total 716800 f16.
// ---------------------------------------------------------------------------

typedef unsigned short u16;
typedef _Float16 f16;
typedef _Float16 half8 __attribute__((ext_vector_type(8)));
typedef float floatx4 __attribute__((ext_vector_type(4)));

#define E_DIM  100
#define H_DIM  256
#define NLAYER 4
#define BATCH  1024
#define NACT   256
#define NROWS_ACT (BATCH * NACT)
#define LN_EPS 1e-5f

#define NET_WIN  0
#define NET_WL(l) (32768 + (l) * 65536)
#define NET_W1   294912
#define NET_W2P  360448
#define POL_SZ   389120
#define VAL_BASE POL_SZ
#define PACK_TOTAL (POL_SZ + 327680)

#define TROWS 32                         // rows per block
#define ACT_BLOCKS (NROWS_ACT / TROWS)   // 8192
#define OBS_BLOCKS (BATCH / TROWS)       // 32 (policy) + 32 (value)

#define WS_VROWS   16
#define WS_ENCOBS  (16 + NROWS_ACT * 4)
#define WS_PACK    (WS_ENCOBS + BATCH * E_DIM * 4)
#define WS_ENCACT  (WS_PACK + PACK_TOTAL * 2)   // f16[NROWS_ACT * 112] ~ 59 MB

__device__ __forceinline__ u16 f2h_u16(float f) {
  union { u16 u; f16 h; } c; c.h = (f16)f; return c.u;
}

__device__ __forceinline__ float wsum(float v) {
#pragma unroll
  for (int off = 1; off < 64; off <<= 1) v += __shfl_xor(v, off, 64);
  return v;
}

// DPP add — VALU-only, no DS pipe traffic.
template <int CTRL>
__device__ __forceinline__ float dpp_add(float v) {
  const int t = __builtin_amdgcn_update_dpp(0, __float_as_int(v), CTRL, 0xF, 0xF, true);
  return v + __int_as_float(t);
}
// 2-step quad sum: every lane gets the sum of its aligned physical quad.
__device__ __forceinline__ float dpp_red4(float v) {
  v = dpp_add<0xB1>(v);    // quad_perm [1,0,3,2]  (xor 1)
  v = dpp_add<0x4E>(v);    // quad_perm [2,3,0,1]  (xor 2)
  return v;
}

__global__ void zero_counter_kernel(int* counter) { *counter = 0; }

// Wave-aggregated compaction (R11).
__global__ void compact_kernel(const int* __restrict__ mask, int n,
                               int* __restrict__ counter,
                               int* __restrict__ rows,
                               u16* __restrict__ logits)
{
  const int i = blockIdx.x * blockDim.x + threadIdx.x;
  const int lane = threadIdx.x & 63;
  bool valid = false;
  if (i < n) {
    valid = (mask[i] != 0);
    if (!valid) logits[i] = (u16)0xFBFF;   // -65504, finite fp16 -inf stand-in
  }
  const unsigned long long bal = __ballot(valid);
  const int cnt = __popcll(bal);
  int base = 0;
  if (lane == 0 && cnt) base = atomicAdd(counter, cnt);
  base = __shfl(base, 0, 64);
  if (valid) {
    const int off = __popcll(bal & ((1ull << lane) - 1ull));
    rows[base + off] = i;
  }
}

__device__ __forceinline__ f16 pack_elem(const f16* __restrict__ W, int li,
                                         int K, int N, int Np)
{
  const int j = li & 7, lane = (li >> 3) & 63, tile = li >> 9;
  const int ntiles = Np >> 4;
  const int k0 = (tile / ntiles) * 32, n0 = (tile % ntiles) * 16;
  const int k = k0 + ((lane >> 4) << 3) + j, n = n0 + (lane & 15);
  return (k < K && n < N) ? W[k * N + n] : (f16)0.f;
}

__global__ void pack_all_kernel(
    const f16* __restrict__ pw_in, const f16* __restrict__ pW,
    const f16* __restrict__ po_w1, const f16* __restrict__ po_w2,
    const f16* __restrict__ vw_in, const f16* __restrict__ vW,
    const f16* __restrict__ vo_w1, f16* __restrict__ dst)
{
  const int i = blockIdx.x * blockDim.x + threadIdx.x;
  if (i >= PACK_TOTAL) return;
  f16 v;
  if (i < 32768)        v = pack_elem(pw_in, i, E_DIM, H_DIM, 256);
  else if (i < 294912) { const int r = i - 32768, l = r >> 16;
                         v = pack_elem(pW + (size_t)l * 65536, r & 65535, 256, 256, 256); }
  else if (i < 360448)  v = pack_elem(po_w1, i - 294912, 256, 256, 256);
  else if (i < 389120)  v = pack_elem(po_w2, i - 360448, 256, E_DIM, 112);
  else if (i < 421888)  v = pack_elem(vw_in, i - 389120, E_DIM, H_DIM, 256);
  else if (i < 684032) { const int r = i - 421888, l = r >> 16;
                         v = pack_elem(vW + (size_t)l * 65536, r & 65535, 256, 256, 256); }
  else                  v = pack_elem(vo_w1, i - 684032, 256, 128, 128);
  dst[i] = v;
}

// wave GEMM: KT k-steps of 32 (KT even), NTC n-tiles, NTA = total n-tiles.
// R18: ping-pong unroll-2. R19: setprio(1) around MFMA bursts.
template <int KT, int NTC, int NTA>
__device__ __forceinline__ void wave_gemm_t(
    const f16* __restrict__ pw, const f16* __restrict__ h16,
    int q, int l15, int lane, int nt_base,
    floatx4 acc0[], floatx4 acc1[])
{
  static_assert((KT & 1) == 0, "KT must be even");
  const f16* pl = pw + (size_t)nt_base * 512 + lane * 8;
  const f16* pa = h16 + l15 * 264 + q * 8;
  const size_t KS = (size_t)NTA * 512;
  half8 b0[NTC], b1[NTC];
#pragma unroll
  for (int t = 0; t < NTC; ++t) b0[t] = *(const half8*)(pl + t * 512);
#pragma unroll 1
  for (int kp = 0; kp < KT / 2 - 1; ++kp) {
#pragma unroll
    for (int t = 0; t < NTC; ++t) b1[t] = *(const half8*)(pl + KS + t * 512);
    {
      const half8 a0 = *(const half8*)(pa);
      const half8 a1 = *(const half8*)(pa + 16 * 264);
      __builtin_amdgcn_s_setprio(1);
#pragma unroll
      for (int t = 0; t < NTC; ++t) {
        acc0[t] = __builtin_amdgcn_mfma_f32_16x16x32_f16(a0, b0[t], acc0[t], 0, 0, 0);
        acc1[t] = __builtin_amdgcn_mfma_f32_16x16x32_f16(a1, b0[t], acc1[t], 0, 0, 0);
      }
      __builtin_amdgcn_s_setprio(0);
    }
#pragma unroll
    for (int t = 0; t < NTC; ++t) b0[t] = *(const half8*)(pl + 2 * KS + t * 512);
    {
      const half8 a0 = *(const half8*)(pa + 32);
      const half8 a1 = *(const half8*)(pa + 16 * 264 + 32);
      __builtin_amdgcn_s_setprio(1);
#pragma unroll
      for (int t = 0; t < NTC; ++t) {
        acc0[t] = __builtin_amdgcn_mfma_f32_16x16x32_f16(a0, b1[t], acc0[t], 0, 0, 0);
        acc1[t] = __builtin_amdgcn_mfma_f32_16x16x32_f16(a1, b1[t], acc1[t], 0, 0, 0);
      }
      __builtin_amdgcn_s_setprio(0);
    }
    pl += 2 * KS;
    pa += 64;
  }
  // final pair (no further prefetch)
#pragma unroll
  for (int t = 0; t < NTC; ++t) b1[t] = *(const half8*)(pl + KS + t * 512);
  {
    const half8 a0 = *(const half8*)(pa);
    const half8 a1 = *(const half8*)(pa + 16 * 264);
    __builtin_amdgcn_s_setprio(1);
#pragma unroll
    for (int t = 0; t < NTC; ++t) {
      acc0[t] = __builtin_amdgcn_mfma_f32_16x16x32_f16(a0, b0[t], acc0[t], 0, 0, 0);
      acc1[t] = __builtin_amdgcn_mfma_f32_16x16x32_f16(a1, b0[t], acc1[t], 0, 0, 0);
    }
    __builtin_amdgcn_s_setprio(0);
  }
  {
    const half8 a0 = *(const half8*)(pa + 32);
    const half8 a1 = *(const half8*)(pa + 16 * 264 + 32);
    __builtin_amdgcn_s_setprio(1);
#pragma unroll
    for (int t = 0; t < NTC; ++t) {
      acc0[t] = __builtin_amdgcn_mfma_f32_16x16x32_f16(a0, b1[t], acc0[t], 0, 0, 0);
      acc1[t] = __builtin_amdgcn_mfma_f32_16x16x32_f16(a1, b1[t], acc1[t], 0, 0, 0);
    }
    __builtin_amdgcn_s_setprio(0);
  }
}

// trunk: input layer + NLAYER residual layers.
// RREG=true: residual in f16 registers (policy). false: fp32 resf (value).
// 8 waves; wave w: rows 0..31, cols w*32..+31. 3 barriers/layer.
template <bool RREG>
__device__ __forceinline__ void run_trunk(
    const f16* __restrict__ packN,
    const f16* __restrict__ b_in, const f16* __restrict__ g_in, const f16* __restrict__ be_in,
    const f16* __restrict__ Br, const f16* __restrict__ Gr, const f16* __restrict__ Ber,
    f16* __restrict__ h16, float2 (*red)[32], float2* __restrict__ stats,
    floatx4 acc[2][2], float* __restrict__ resf, f16* __restrict__ res16,
    int tid, int q, int l15, int w, int n0)
{
#pragma unroll 1
  for (int l = 0; l <= NLAYER; ++l) {
    const f16* pw; const f16* bias; const f16* g; const f16* be;
    if (l == 0) { pw = packN + NET_WIN; bias = b_in; g = g_in; be = be_in; }
    else {
      pw = packN + NET_WL(l - 1); bias = Br + (l - 1) * H_DIM;
      g = Gr + (l - 1) * H_DIM;   be = Ber + (l - 1) * H_DIM;
    }
#pragma unroll
    for (int t = 0; t < 2; ++t) {
      const float bv = (float)bias[n0 + t * 16 + l15];
      acc[0][t] = (floatx4){bv, bv, bv, bv};
      acc[1][t] = acc[0][t];
    }
    if (l == 0) wave_gemm_t<4, 2, 16>(pw, h16, q, l15, tid & 63, w * 2, acc[0], acc[1]);
    else        wave_gemm_t<8, 2, 16>(pw, h16, q, l15, tid & 63, w * 2, acc[0], acc[1]);

    // partial sums over this wave's 32 cols — 2-step DPP (quad sums),
    // quad leaders (l15%4==0) write red[R][w*4 + quad]
#pragma unroll
    for (int mt = 0; mt < 2; ++mt)
#pragma unroll
      for (int reg = 0; reg < 4; ++reg) {
        const float v0 = fmaxf(acc[mt][0][reg], 0.f);
        const float v1 = fmaxf(acc[mt][1][reg], 0.f);
        acc[mt][0][reg] = v0; acc[mt][1][reg] = v1;   // keep relu'd
        const float s  = dpp_red4(v0 + v1);
        const float s2 = dpp_red4(v0 * v0 + v1 * v1);
        if ((l15 & 3) == 0) {
          const int R = mt * 16 + q * 4 + reg;
          red[R][w * 4 + (l15 >> 2)] = (float2){s, s2};
        }
      }
    __syncthreads();

    // centralized row stats: 32 threads, one row each (32 partials/row)
    if (tid < TROWS) {
      const float4* rp = (const float4*)&red[tid][0];
      float s = 0.f, s2 = 0.f;
#pragma unroll
      for (int i = 0; i < 16; ++i) {
        const float4 r = rp[i];
        s += r.x + r.z; s2 += r.y + r.w;
      }
      const float mean = s * (1.f / 256.f);
      const float var  = s2 * (1.f / 256.f) - mean * mean;
      stats[tid] = (float2){mean, 1.f / sqrtf(var + LN_EPS)};
    }
    __syncthreads();

    const float gf0 = (float)g[n0 + l15],       gf1 = (float)g[n0 + 16 + l15];
    const float bf0 = (float)be[n0 + l15],      bf1 = (float)be[n0 + 16 + l15];
#pragma unroll
    for (int mt = 0; mt < 2; ++mt)
#pragma unroll
      for (int reg = 0; reg < 4; ++reg) {
        const int R = mt * 16 + q * 4 + reg;
        const float2 st = stats[R];
        const float a0c = st.y * gf0;
        const float b0c = fmaf(-st.x, a0c, bf0);
        const float a1c = st.y * gf1;
        const float b1c = fmaf(-st.x, a1c, bf1);
#pragma unroll
        for (int t = 0; t < 2; ++t) {
          const int col = n0 + t * 16 + l15;
          const int ri = (mt * 2 + t) * 4 + reg;
          const float vv = fmaf(acc[mt][t][reg],
                                t == 0 ? a0c : a1c, t == 0 ? b0c : b1c);
          float rprev;
          if (l == 0) rprev = 0.f;
          else rprev = RREG ? (float)res16[ri] : resf[ri];
          const float r = rprev + vv;
          if (RREG) res16[ri] = (f16)r; else resf[ri] = r;
          h16[R * 264 + col] = (f16)r;
        }
      }
    __syncthreads();
  }
}

// policy heads: h1 = relu(h @ w1 + b1); enc = h1 @ w2 + b2 -> encf (32x112 f32)
__device__ __forceinline__ void policy_heads(
    const f16* __restrict__ packN,
    const f16* __restrict__ b1, const f16* __restrict__ b2,
    f16* __restrict__ h16, floatx4 acc[2][2],
    int tid, int q, int l15, int w, int n0)
{
#pragma unroll
  for (int t = 0; t < 2; ++t) {
    const float bv = (float)b1[n0 + t * 16 + l15];
    acc[0][t] = (floatx4){bv, bv, bv, bv};
    acc[1][t] = acc[0][t];
  }
  wave_gemm_t<8, 2, 16>(packN + NET_W1, h16, q, l15, tid & 63, w * 2, acc[0], acc[1]);
  __syncthreads();
#pragma unroll
  for (int mt = 0; mt < 2; ++mt)
#pragma unroll
    for (int reg = 0; reg < 4; ++reg) {
      const int R = mt * 16 + q * 4 + reg;
#pragma unroll
      for (int t = 0; t < 2; ++t)
        h16[R * 264 + n0 + t * 16 + l15] = (f16)fmaxf(acc[mt][t][reg], 0.f);
    }
  __syncthreads();

  // W2: 7 n-tiles; waves 0..6 take one tile each
  if (w < 7) {
    const int col = w * 16 + l15;
    const float bv = (col < E_DIM) ? (float)b2[col] : 0.f;
    acc[0][0] = (floatx4){bv, bv, bv, bv};
    acc[1][0] = acc[0][0];
    wave_gemm_t<8, 1, 7>(packN + NET_W2P, h16, q, l15, tid & 63, w, acc[0], acc[1]);
  }
  __syncthreads();

  float* encf = (float*)h16;   // 32 x 112 fp32 (14336 B <= 16896 B)
  if (w < 7) {
#pragma unroll
    for (int mt = 0; mt < 2; ++mt)
#pragma unroll
      for (int reg = 0; reg < 4; ++reg) {
        const int R = mt * 16 + q * 4 + reg;
        encf[R * 112 + w * 16 + l15] = acc[mt][0][reg];
      }
  }
  __syncthreads();
}

// Merged trunk kernel (8 waves, 32 rows per block, 80-reg cap, no spill).
//  blockIdx 0..31  : policy obs-encode (1024 rows)  -> enc_obs (f32)
//  blockIdx 32..63 : value net (1024 rows)          -> value   (f16)
//  blockIdx 64..   : act-encode on compacted rows   -> enc_act (f16, ws)
__global__ __launch_bounds__(512, 6)
void trunk_kernel(
    const f16* __restrict__ obs, const f16* __restrict__ xact,
    const int* __restrict__ vrows, const int* __restrict__ counter,
    const f16* __restrict__ packP, const f16* __restrict__ packV,
    // policy params
    const f16* __restrict__ pb_in, const f16* __restrict__ pg_in, const f16* __restrict__ pbe_in,
    const f16* __restrict__ pB, const f16* __restrict__ pG, const f16* __restrict__ pBe,
    const f16* __restrict__ po_b1, const f16* __restrict__ po_b2,
    // value params
    const f16* __restrict__ vb_in, const f16* __restrict__ vg_in, const f16* __restrict__ vbe_in,
    const f16* __restrict__ vB, const f16* __restrict__ vG, const f16* __restrict__ vBe,
    const f16* __restrict__ vo_b1, const f16* __restrict__ vo_b2, const f16* __restrict__ vo_w2,
    float* __restrict__ enc_obs_out, f16* __restrict__ enc_act_out,
    u16* __restrict__ value_out)
{
  __shared__ __align__(16) f16 h16[TROWS * 264];
  __shared__ __align__(16) float2 red[TROWS][32];
  __shared__ float2 stats[TROWS];

  const int tid  = threadIdx.x;
  const int lane = tid & 63;
  const int w    = tid >> 6;          // 0..7
  const int l15 = lane & 15, q = lane >> 4;
  const int n0 = w * 32;              // wave cols: w*32 .. w*32+31

  floatx4 acc[2][2];

  if (blockIdx.x >= 2 * OBS_BLOCKS) {
    // ---------------- act-encode role ----------------
    const int count = *counter;
    const int base = (blockIdx.x - 2 * OBS_BLOCKS) * TROWS;
    if (base >= count) return;

    for (int idx = tid; idx < TROWS * 128; idx += 512) {
      const int r = idx >> 7, c = idx & 127;
      const int gr = base + r;
      f16 v = (f16)0.f;
      if (c < E_DIM && gr < count) v = xact[(size_t)vrows[gr] * E_DIM + c];
      h16[r * 264 + c] = v;
    }
    __syncthreads();

    f16 res16[16];
    run_trunk<true>(packP, pb_in, pg_in, pbe_in, pB, pG, pBe, h16, red, stats,
                    acc, nullptr, res16, tid, q, l15, w, n0);
    policy_heads(packP, po_b1, po_b2, h16, acc, tid, q, l15, w, n0);

    const float* encf = (const float*)h16;
    for (int idx = tid; idx < TROWS * 112; idx += 512) {
      const int r = idx / 112, c = idx - r * 112;
      enc_act_out[(size_t)(base + r) * 112 + c] = (f16)encf[r * 112 + c];
    }
    return;
  }

  // ---------------- obs / value roles ----------------
  const bool isv = blockIdx.x >= OBS_BLOCKS;
  const int base = (isv ? (blockIdx.x - OBS_BLOCKS) : blockIdx.x) * TROWS;

  for (int idx = tid; idx < TROWS * 128; idx += 512) {
    const int r = idx >> 7, c = idx & 127;
    h16[r * 264 + c] = (c < E_DIM) ? obs[(size_t)(base + r) * E_DIM + c] : (f16)0.f;
  }
  __syncthreads();

  if (!isv) {
    f16 res16[16];
    run_trunk<true>(packP, pb_in, pg_in, pbe_in, pB, pG, pBe, h16, red, stats,
                    acc, nullptr, res16, tid, q, l15, w, n0);
    policy_heads(packP, po_b1, po_b2, h16, acc, tid, q, l15, w, n0);
    const float* encf = (const float*)h16;
    for (int idx = tid; idx < TROWS * E_DIM; idx += 512) {
      const int r = idx / E_DIM, c = idx - r * E_DIM;
      enc_obs_out[(size_t)(base + r) * E_DIM + c] = encf[r * 112 + c];
    }
  } else {
    float resf[16];
    run_trunk<false>(packV, vb_in, vg_in, vbe_in, vB, vG, vBe, h16, red, stats,
                     acc, resf, nullptr, tid, q, l15, w, n0);
    // value head1: relu(h @ vo_w1 + vo_b1), N=128 = 8 n-tiles, 1 per wave
    {
      const float bv = (float)vo_b1[w * 16 + l15];
      acc[0][0] = (floatx4){bv, bv, bv, bv};
      acc[1][0] = acc[0][0];
    }
    wave_gemm_t<8, 1, 8>(packV + NET_W1, h16, q, l15, lane, w, acc[0], acc[1]);
    __syncthreads();
    float* encf = (float*)h16;   // 32 x 128 fp32 (16384 B <= 16896 B)
#pragma unroll
    for (int mt = 0; mt < 2; ++mt)
#pragma unroll
      for (int reg = 0; reg < 4; ++reg) {
        const int R = mt * 16 + q * 4 + reg;
        encf[R * 128 + w * 16 + l15] = fmaxf(acc[mt][0][reg], 0.f);
      }
    __syncthreads();
    const float w2a = (float)vo_w2[lane], w2b = (float)vo_w2[lane + 64];
    const float b2v = (float)vo_b2[0];
    for (int j = 0; j < 4; ++j) {
      const int r = w * 4 + j;
      const float p = encf[r * 128 + lane] * w2a + encf[r * 128 + lane + 64] * w2b;
      const float tot = wsum(p);
      if (lane == 0) value_out[base + r] = f2h_u16(tot + b2v);
    }
  }
}

// epilogue: logits[vrow] = (enc_obs[bb] . enc_act[gr]) / sqrt(E)
__global__ __launch_bounds__(256)
void logits_kernel(const int* __restrict__ vrows, const int* __restrict__ counter,
                   const f16* __restrict__ enc_act, const float* __restrict__ enc_obs,
                   u16* __restrict__ logits)
{
  const int count = *counter;
  const int lane = threadIdx.x & 63;
  const int nw = (gridDim.x * blockDim.x) >> 6;
  for (int gr = (blockIdx.x * blockDim.x + threadIdx.x) >> 6; gr < count; gr += nw) {
    const int vrow = vrows[gr];
    const int bb = vrow >> 8;   // A = 256
    const float* ob = enc_obs + (size_t)bb * E_DIM;
    const f16*   ar = enc_act + (size_t)gr * 112;
    float p = (float)ar[lane] * ob[lane];
    if (lane + 64 < E_DIM) p += (float)ar[lane + 64] * ob[lane + 64];
    const float tot = wsum(p);
    if (lane == 0) logits[vrow] = f2h_u16(tot * 0.1f);   // 1/sqrt(100)
  }
}

// ============================ launch =======================================
extern "C" void kernel_launch(void* const* d_in, const int* in_sizes, int n_in,
                              void* d_out, int out_size, void* d_ws, size_t ws_size,
                              hipStream_t stream)
{
  const f16* obs   = (const f16*)d_in[0];
  const f16* actE  = (const f16*)d_in[1];
  const int* mask  = (const int*)d_in[2];
  const f16* pw_in = (const f16*)d_in[3];
  const f16* pb_in = (const f16*)d_in[4];
  const f16* pg_in = (const f16*)d_in[5];
  const f16* pbe_in= (const f16*)d_in[6];
  const f16* pW    = (const f16*)d_in[7];
  const f16* pB    = (const f16*)d_in[8];
  const f16* pG    = (const f16*)d_in[9];
  const f16* pBe   = (const f16*)d_in[10];
  const f16* po_w1 = (const f16*)d_in[11];
  const f16* po_b1 = (const f16*)d_in[12];
  const f16* po_w2 = (const f16*)d_in[13];
  const f16* po_b2 = (const f16*)d_in[14];
  const f16* vw_in = (const f16*)d_in[15];
  const f16* vb_in = (const f16*)d_in[16];
  const f16* vg_in = (const f16*)d_in[17];
  const f16* vbe_in= (const f16*)d_in[18];
  const f16* vW    = (const f16*)d_in[19];
  const f16* vB    = (const f16*)d_in[20];
  const f16* vG    = (const f16*)d_in[21];
  const f16* vBe   = (const f16*)d_in[22];
  const f16* vo_w1 = (const f16*)d_in[23];
  const f16* vo_b1 = (const f16*)d_in[24];
  const f16* vo_w2 = (const f16*)d_in[25];
  const f16* vo_b2 = (const f16*)d_in[26];

  u16* logits = (u16*)d_out;
  u16* value  = (u16*)d_out + NROWS_ACT;

  int*   counter = (int*)d_ws;
  int*   vrows   = (int*)((char*)d_ws + WS_VROWS);
  float* enc_obs = (float*)((char*)d_ws + WS_ENCOBS);
  f16*   packW   = (f16*)((char*)d_ws + WS_PACK);
  f16*   enc_act = (f16*)((char*)d_ws + WS_ENCACT);

  zero_counter_kernel<<<1, 1, 0, stream>>>(counter);
  compact_kernel<<<NROWS_ACT / 256, 256, 0, stream>>>(mask, NROWS_ACT, counter,
                                                      vrows, logits);
  pack_all_kernel<<<(PACK_TOTAL + 255) / 256, 256, 0, stream>>>(
      pw_in, pW, po_w1, po_w2, vw_in, vW, vo_w1, packW);

  trunk_kernel<<<ACT_BLOCKS + 2 * OBS_BLOCKS, 512, 0, stream>>>(
      obs, actE, vrows, counter, packW, packW + VAL_BASE,
      pb_in, pg_in, pbe_in, pB, pG, pBe, po_b1, po_b2,
      vb_in, vg_in, vbe_in, vB, vG, vBe, vo_b1, vo_b2, vo_w2,
      enc_obs, enc_act, value);

  logits_kernel<<<2048, 256, 0, stream>>>(vrows, counter, enc_act, enc_obs, logits);
}